// Round 1
// baseline (2268.350 us; speedup 1.0000x reference)
//
#include <hip/hip_runtime.h>
#include <hip/hip_bf16.h>

// ---------------------------------------------------------------------------
// CosineAttention forward, fp32 correctness-first baseline.
// b=16, c=512, h=w=32 -> seq=1024, heads=8, head_dim=64.
//
// Pipeline:
//  1) wnorm_kernel      : normalize w_attn (1536x512) and w_proj (512x512)
//  2) gemm_kernel<0>    : x_proj[b][1536][1024] = wn_attn @ x[b]
//  3) pixnorm_kernel    : in-place pixel_norm over heads axis (groups of 8
//                         channels at stride 64) for q,k,v
//  4) attn_kernel       : per (b, head, 64-query block) flash attention,
//                         writes y[b][n*64+d][s]   (d-major == proj layout)
//  5) gemm_kernel<1>    : out = mp_add(x, wn_proj @ y)
// ---------------------------------------------------------------------------

#define SEQ   1024
#define CCH   512
#define NHEAD 8
#define HD    64

// ---------------- weight normalization ----------------
// wn[o][i] = w[o][i] / (sqrt(sum_i w^2) + EPS*sqrt(512))
__global__ __launch_bounds__(256) void wnorm_kernel(
    const float* __restrict__ wa, const float* __restrict__ wp,
    float* __restrict__ wna, float* __restrict__ wnp) {
  int o = blockIdx.x;
  const float* src;
  float* dst;
  if (o < 1536) { src = wa + (size_t)o * 512; dst = wna + (size_t)o * 512; }
  else          { src = wp + (size_t)(o - 1536) * 512; dst = wnp + (size_t)(o - 1536) * 512; }
  int tid = threadIdx.x;
  float a = src[tid], b = src[tid + 256];
  float ss = a * a + b * b;
#pragma unroll
  for (int off = 32; off > 0; off >>= 1) ss += __shfl_down(ss, off, 64);
  __shared__ float wsum[4];
  if ((tid & 63) == 0) wsum[tid >> 6] = ss;
  __syncthreads();
  float tot = wsum[0] + wsum[1] + wsum[2] + wsum[3];
  // w / ((EPS + n/sqrt(F)) * sqrt(F)) == w / (n + EPS*sqrt(F)),  F = 512
  float r = 1.0f / (sqrtf(tot) + 2.2627416997969522e-3f);
  dst[tid] = a * r;
  dst[tid + 256] = b * r;
}

// ---------------- fp32 tiled GEMM:  Out[b] = W[MxK] @ Xin[b][KxN] ----------
// FUSE=1: Out = 0.9191450*resid + 0.3939193*Out   (mp_add with t=0.3)
template <int FUSE>
__global__ __launch_bounds__(256) void gemm_kernel(
    const float* __restrict__ W, const float* __restrict__ Xin,
    float* __restrict__ Out, const float* __restrict__ resid,
    int M, int K, int N) {
  __shared__ float As[16][65];  // [kk][m]
  __shared__ float Bs[16][65];  // [kk][n]
  int tid = threadIdx.x;
  int tx = tid & 15, ty = tid >> 4;
  int n0 = blockIdx.x * 64, m0 = blockIdx.y * 64, b = blockIdx.z;
  const float* Xb = Xin + (size_t)b * K * N;
  float acc[4][4] = {};
  int lm = tid >> 2;             // A row 0..63
  int lk = (tid & 3) * 4;        // A k offset {0,4,8,12}
  int bn = tid & 63, bk = tid >> 6;
  for (int k0 = 0; k0 < K; k0 += 16) {
    float4 av = *(const float4*)(W + (size_t)(m0 + lm) * K + k0 + lk);
    As[lk + 0][lm] = av.x; As[lk + 1][lm] = av.y;
    As[lk + 2][lm] = av.z; As[lk + 3][lm] = av.w;
#pragma unroll
    for (int i = 0; i < 4; ++i)
      Bs[bk + i * 4][bn] = Xb[(size_t)(k0 + bk + i * 4) * N + n0 + bn];
    __syncthreads();
#pragma unroll
    for (int kk = 0; kk < 16; ++kk) {
      float a[4], bv[4];
#pragma unroll
      for (int i = 0; i < 4; ++i) a[i] = As[kk][ty * 4 + i];
#pragma unroll
      for (int j = 0; j < 4; ++j) bv[j] = Bs[kk][tx * 4 + j];
#pragma unroll
      for (int i = 0; i < 4; ++i)
#pragma unroll
        for (int j = 0; j < 4; ++j) acc[i][j] = fmaf(a[i], bv[j], acc[i][j]);
    }
    __syncthreads();
  }
#pragma unroll
  for (int i = 0; i < 4; ++i) {
    size_t idx = (size_t)b * M * N + (size_t)(m0 + ty * 4 + i) * N + n0 + tx * 4;
    float4 v = make_float4(acc[i][0], acc[i][1], acc[i][2], acc[i][3]);
    if (FUSE) {
      float4 r = *(const float4*)(resid + idx);
      v.x = 0.9191450300180578f * r.x + 0.39391929857916763f * v.x;
      v.y = 0.9191450300180578f * r.y + 0.39391929857916763f * v.y;
      v.z = 0.9191450300180578f * r.z + 0.39391929857916763f * v.z;
      v.w = 0.9191450300180578f * r.w + 0.39391929857916763f * v.w;
    }
    *(float4*)(Out + idx) = v;
  }
}

// ---------------- pixel_norm over heads axis (in place) --------------------
// For fixed (b, g in {q,k,v}, d, s): normalize the 8 values
// xp[b][g*512 + n*64 + d][s], n=0..7 by rsqrt(mean(sq)+EPS).
__global__ __launch_bounds__(256) void pixnorm_kernel(float* __restrict__ xp) {
  size_t id = (size_t)blockIdx.x * 256 + threadIdx.x;  // 16*3*64*1024 total
  int s = id & 1023;
  int d = (int)((id >> 10) & 63);
  int gb = (int)(id >> 16);   // 0..47
  int g = gb % 3, b = gb / 3;
  float* base = xp + ((size_t)(b * 1536 + g * 512 + d) * 1024 + s);
  float v[8];
  float ss = 0.f;
#pragma unroll
  for (int n = 0; n < 8; ++n) {
    v[n] = base[(size_t)n * 65536];  // 64*1024
    ss += v[n] * v[n];
  }
  float f = rsqrtf(ss * 0.125f + 1e-4f);
#pragma unroll
  for (int n = 0; n < 8; ++n) base[(size_t)n * 65536] = v[n] * f;
}

// ---------------- flash attention, fp32 ------------------------------------
// Grid (qb=16, n=8, b=16), 256 threads. q/k/v stored d-major: [hd][seq]
// slices of xp. Output y[b][n*64+d][s] (d-major) -> direct proj-GEMM input.
__global__ __launch_bounds__(256) void attn_kernel(const float* __restrict__ xp,
                                                   float* __restrict__ y) {
  __shared__ float Qs[64][65];   // [d][q], pre-scaled by 1/8
  __shared__ float KVs[64][65];  // [d][k], K then V (time-shared)
  __shared__ float Ps[64][65];   // [q][k]
  int qb = blockIdx.x, n = blockIdx.y, b = blockIdx.z;
  int tid = threadIdx.x;
  int qrow = tid >> 2;        // 0..63 query within block
  int l4 = tid & 3;           // 0..3
  int k0 = l4 * 16;           // this thread's 16-wide k slice
  int d0 = l4 * 16;           // this thread's 16-wide d slice (for O)
  const size_t bbase = (size_t)b * 1536 * 1024;
  const float* qg = xp + bbase + (size_t)(n * 64) * 1024 + qb * 64;
  const float* kg = xp + bbase + (size_t)(512 + n * 64) * 1024;
  const float* vg = xp + bbase + (size_t)(1024 + n * 64) * 1024;

#pragma unroll
  for (int i = 0; i < 16; ++i) {
    int e = tid + i * 256;
    int d = e >> 6, q = e & 63;
    Qs[d][q] = qg[(size_t)d * 1024 + q] * 0.125f;  // fold 1/sqrt(hd)
  }
  float m_run = -1e30f, l_run = 0.f;
  float acc[16];
#pragma unroll
  for (int i = 0; i < 16; ++i) acc[i] = 0.f;
  __syncthreads();

  for (int kb = 0; kb < 16; ++kb) {
    // ---- load K tile
#pragma unroll
    for (int i = 0; i < 16; ++i) {
      int e = tid + i * 256;
      int d = e >> 6, k = e & 63;
      KVs[d][k] = kg[(size_t)d * 1024 + kb * 64 + k];
    }
    __syncthreads();
    // ---- scores for (qrow, k0..k0+15)
    float s[16];
#pragma unroll
    for (int j = 0; j < 16; ++j) s[j] = 0.f;
    for (int d = 0; d < 64; ++d) {
      float qv = Qs[d][qrow];
#pragma unroll
      for (int j = 0; j < 16; ++j) s[j] = fmaf(qv, KVs[d][k0 + j], s[j]);
    }
    __syncthreads();  // done reading K
    // ---- load V tile (reuse KVs)
#pragma unroll
    for (int i = 0; i < 16; ++i) {
      int e = tid + i * 256;
      int d = e >> 6, k = e & 63;
      KVs[d][k] = vg[(size_t)d * 1024 + kb * 64 + k];
    }
    // ---- online softmax (row qrow shared by 4 lanes)
    float mt = s[0];
#pragma unroll
    for (int j = 1; j < 16; ++j) mt = fmaxf(mt, s[j]);
    mt = fmaxf(mt, __shfl_xor(mt, 1, 64));
    mt = fmaxf(mt, __shfl_xor(mt, 2, 64));
    float m_new = fmaxf(m_run, mt);
    float fscale = __expf(m_run - m_new);
    float ts = 0.f;
#pragma unroll
    for (int j = 0; j < 16; ++j) {
      float p = __expf(s[j] - m_new);
      Ps[qrow][k0 + j] = p;
      ts += p;
    }
    ts += __shfl_xor(ts, 1, 64);
    ts += __shfl_xor(ts, 2, 64);
    l_run = l_run * fscale + ts;
    m_run = m_new;
#pragma unroll
    for (int i = 0; i < 16; ++i) acc[i] *= fscale;
    __syncthreads();  // V + P visible
    // ---- O[qrow][d0+i] += sum_k P[qrow][k] * V[d0+i][k]
    for (int k = 0; k < 64; ++k) {
      float pv = Ps[qrow][k];
#pragma unroll
      for (int i = 0; i < 16; ++i) acc[i] = fmaf(pv, KVs[d0 + i][k], acc[i]);
    }
    __syncthreads();  // before next tile overwrites KVs/Ps
  }
  float invl = 1.0f / l_run;
#pragma unroll
  for (int i = 0; i < 16; ++i) {
    y[(size_t)(b * 512 + n * 64 + d0 + i) * 1024 + qb * 64 + qrow] = acc[i] * invl;
  }
}

// ---------------------------------------------------------------------------
extern "C" void kernel_launch(void* const* d_in, const int* in_sizes, int n_in,
                              void* d_out, int out_size, void* d_ws, size_t ws_size,
                              hipStream_t stream) {
  const float* x      = (const float*)d_in[0];  // [16][512][1024]
  const float* w_attn = (const float*)d_in[1];  // [1536][512]
  const float* w_proj = (const float*)d_in[2];  // [512][512]
  float* out = (float*)d_out;

  float* ws = (float*)d_ws;
  float* wn_attn = ws;                               // 1536*512
  float* wn_proj = wn_attn + 1536 * 512;             // 512*512
  float* xp      = wn_proj + 512 * 512;              // 16*1536*1024
  float* y       = xp + (size_t)16 * 1536 * 1024;    // 16*512*1024

  // 1) weight normalization
  wnorm_kernel<<<dim3(2048), dim3(256), 0, stream>>>(w_attn, w_proj, wn_attn, wn_proj);
  // 2) qkv projection
  gemm_kernel<0><<<dim3(16, 24, 16), dim3(256), 0, stream>>>(
      wn_attn, x, xp, nullptr, 1536, 512, 1024);
  // 3) pixel norm (in place)
  pixnorm_kernel<<<dim3(12288), dim3(256), 0, stream>>>(xp);
  // 4) attention
  attn_kernel<<<dim3(16, 8, 16), dim3(256), 0, stream>>>(xp, y);
  // 5) output projection + mp_add
  gemm_kernel<1><<<dim3(16, 8, 16), dim3(256), 0, stream>>>(
      wn_proj, y, out, x, 512, 512, 1024);
}

// Round 2
// 771.503 us; speedup vs baseline: 2.9402x; 2.9402x over previous
//
#include <hip/hip_runtime.h>
#include <hip/hip_bf16.h>

// ---------------------------------------------------------------------------
// CosineAttention forward.  b=16, c=512, h=w=32 -> seq=1024, heads=8, hd=64.
//
// Pipeline:
//  1) wnorm_kernel    : normalize w_attn (1536x512) and w_proj (512x512)
//  2) gemm_kernel<0>  : xp[b][1536][1024] = wn_attn @ x[b]          (fp32)
//  3) scale_v_kernel  : heads-axis pixel_norm scale f[b][g][d][s];
//                       emits normalized V as bf16 [bn][d][s]
//  4) repack_qk       : normalized Q,K as bf16 [bn][s][d] (LDS transpose);
//                       Q gets 0.125*log2(e) folded in
//  5) attn_mfma       : flash attention, 16x16x32 bf16 MFMA, swapped
//                       operands (S^T / O^T), writes y[b][ch][s] fp32
//  6) gemm_kernel<1>  : out = mp_add(x, wn_proj @ y)                (fp32)
// ---------------------------------------------------------------------------

typedef __attribute__((ext_vector_type(8))) short short8;
typedef __attribute__((ext_vector_type(4))) float f32x4;

__device__ inline unsigned short f2bf(float v) {
  __hip_bfloat16 h = __float2bfloat16(v);
  return *reinterpret_cast<unsigned short*>(&h);
}

// ---------------- weight normalization ----------------
__global__ __launch_bounds__(256) void wnorm_kernel(
    const float* __restrict__ wa, const float* __restrict__ wp,
    float* __restrict__ wna, float* __restrict__ wnp) {
  int o = blockIdx.x;
  const float* src;
  float* dst;
  if (o < 1536) { src = wa + (size_t)o * 512; dst = wna + (size_t)o * 512; }
  else          { src = wp + (size_t)(o - 1536) * 512; dst = wnp + (size_t)(o - 1536) * 512; }
  int tid = threadIdx.x;
  float a = src[tid], b = src[tid + 256];
  float ss = a * a + b * b;
#pragma unroll
  for (int off = 32; off > 0; off >>= 1) ss += __shfl_down(ss, off, 64);
  __shared__ float wsum[4];
  if ((tid & 63) == 0) wsum[tid >> 6] = ss;
  __syncthreads();
  float tot = wsum[0] + wsum[1] + wsum[2] + wsum[3];
  float r = 1.0f / (sqrtf(tot) + 2.2627416997969522e-3f);  // n + EPS*sqrt(512)
  dst[tid] = a * r;
  dst[tid + 256] = b * r;
}

// ---------------- fp32 tiled GEMM:  Out[b] = W[MxK] @ Xin[b][KxN] ----------
template <int FUSE>
__global__ __launch_bounds__(256) void gemm_kernel(
    const float* __restrict__ W, const float* __restrict__ Xin,
    float* __restrict__ Out, const float* __restrict__ resid,
    int M, int K, int N) {
  __shared__ float As[16][65];
  __shared__ float Bs[16][65];
  int tid = threadIdx.x;
  int tx = tid & 15, ty = tid >> 4;
  int n0 = blockIdx.x * 64, m0 = blockIdx.y * 64, b = blockIdx.z;
  const float* Xb = Xin + (size_t)b * K * N;
  float acc[4][4] = {};
  int lm = tid >> 2;
  int lk = (tid & 3) * 4;
  int bn = tid & 63, bk = tid >> 6;
  for (int k0 = 0; k0 < K; k0 += 16) {
    float4 av = *(const float4*)(W + (size_t)(m0 + lm) * K + k0 + lk);
    As[lk + 0][lm] = av.x; As[lk + 1][lm] = av.y;
    As[lk + 2][lm] = av.z; As[lk + 3][lm] = av.w;
#pragma unroll
    for (int i = 0; i < 4; ++i)
      Bs[bk + i * 4][bn] = Xb[(size_t)(k0 + bk + i * 4) * N + n0 + bn];
    __syncthreads();
#pragma unroll
    for (int kk = 0; kk < 16; ++kk) {
      float a[4], bv[4];
#pragma unroll
      for (int i = 0; i < 4; ++i) a[i] = As[kk][ty * 4 + i];
#pragma unroll
      for (int j = 0; j < 4; ++j) bv[j] = Bs[kk][tx * 4 + j];
#pragma unroll
      for (int i = 0; i < 4; ++i)
#pragma unroll
        for (int j = 0; j < 4; ++j) acc[i][j] = fmaf(a[i], bv[j], acc[i][j]);
    }
    __syncthreads();
  }
#pragma unroll
  for (int i = 0; i < 4; ++i) {
    size_t idx = (size_t)b * M * N + (size_t)(m0 + ty * 4 + i) * N + n0 + tx * 4;
    float4 v = make_float4(acc[i][0], acc[i][1], acc[i][2], acc[i][3]);
    if (FUSE) {
      float4 r = *(const float4*)(resid + idx);
      v.x = 0.9191450300180578f * r.x + 0.39391929857916763f * v.x;
      v.y = 0.9191450300180578f * r.y + 0.39391929857916763f * v.y;
      v.z = 0.9191450300180578f * r.z + 0.39391929857916763f * v.z;
      v.w = 0.9191450300180578f * r.w + 0.39391929857916763f * v.w;
    }
    *(float4*)(Out + idx) = v;
  }
}

// ---------------- scale (pixel_norm over heads) + V emit -------------------
// f[b][g][d][s] = rsqrt(mean_n xp^2 + 1e-4) for g in {q,k};
// V (g==2) written directly as bf16 [b*8+n][d][s].
__global__ __launch_bounds__(256) void scale_v_kernel(
    const float* __restrict__ xp, float* __restrict__ f,
    __hip_bfloat16* __restrict__ v_ds) {
  size_t id = (size_t)blockIdx.x * 256 + threadIdx.x;  // 16*3*64*1024
  int s = id & 1023;
  int d = (int)((id >> 10) & 63);
  int gb = (int)(id >> 16);
  int g = gb % 3, b = gb / 3;
  const float* base = xp + ((size_t)(b * 1536 + g * 512 + d) * 1024 + s);
  float v[8];
  float ss = 0.f;
#pragma unroll
  for (int n = 0; n < 8; ++n) {
    v[n] = base[(size_t)n * 65536];
    ss += v[n] * v[n];
  }
  float fv = rsqrtf(ss * 0.125f + 1e-4f);
  if (g == 2) {
#pragma unroll
    for (int n = 0; n < 8; ++n)
      v_ds[((size_t)((b * 8 + n) * 64 + d)) * 1024 + s] = __float2bfloat16(v[n] * fv);
  } else {
    f[((size_t)((b * 2 + g) * 64 + d)) * 1024 + s] = fv;
  }
}

// ---------------- repack Q,K to seq-major bf16 [bn][s][d] ------------------
// Applies pixel_norm scale; Q additionally scaled by 0.125*log2(e) so the
// softmax can use exp2 directly. LDS transpose, coalesced in and out.
__global__ __launch_bounds__(256) void repack_qk(
    const float* __restrict__ xp, const float* __restrict__ f,
    __hip_bfloat16* __restrict__ q_sd, __hip_bfloat16* __restrict__ k_sd) {
  __shared__ __align__(16) unsigned short trans[64][68];  // [s][d], pad 4
  int s0 = blockIdx.x * 64;
  int n = blockIdx.y;
  int g = blockIdx.z & 1, b = blockIdx.z >> 1;
  int t = threadIdx.x;
  int sl = t & 63, dg = t >> 6;  // dg in 0..3, d-range dg*16..+15
  const float* src = xp + ((size_t)(b * 1536 + g * 512 + n * 64 + dg * 16) * 1024) + s0 + sl;
  const float* fs = f + ((size_t)((b * 2 + g) * 64 + dg * 16) * 1024) + s0 + sl;
  float qm = g ? 1.0f : 0.18033688011112042f;  // 0.125 * log2(e) folded into Q
#pragma unroll
  for (int i = 0; i < 16; i += 2) {
    float v0 = src[(size_t)i * 1024] * (fs[(size_t)i * 1024] * qm);
    float v1 = src[(size_t)(i + 1) * 1024] * (fs[(size_t)(i + 1) * 1024] * qm);
    unsigned pr = (unsigned)f2bf(v0) | ((unsigned)f2bf(v1) << 16);
    *(unsigned*)&trans[sl][dg * 16 + i] = pr;
  }
  __syncthreads();
  int sw = t >> 2, dw = (t & 3) * 16;
  uint2 r0 = *(uint2*)&trans[sw][dw + 0];
  uint2 r1 = *(uint2*)&trans[sw][dw + 4];
  uint2 r2 = *(uint2*)&trans[sw][dw + 8];
  uint2 r3 = *(uint2*)&trans[sw][dw + 12];
  __hip_bfloat16* dst = (g ? k_sd : q_sd) +
      ((size_t)((b * 8 + n) * 1024 + s0 + sw) * 64 + dw);
  uint4 o0 = {r0.x, r0.y, r1.x, r1.y};
  uint4 o1 = {r2.x, r2.y, r3.x, r3.y};
  *(uint4*)dst = o0;
  *(uint4*)((char*)dst + 16) = o1;
}

// ---------------- flash attention, bf16 MFMA -------------------------------
// Grid (qb=8 [128 q each], bn=128). 4 waves; wave w owns 32 q (2 subtiles).
// Swapped operands: S^T = mfma(K, Q^T), O^T = mfma(V^T, P^T).
// K/V tiles (64 keys) double-buffered in LDS with XOR swizzle
// byte ^= ((row&7)<<4) applied identically on write and read.
__global__ __launch_bounds__(256) void attn_mfma(
    const __hip_bfloat16* __restrict__ q_sd, const __hip_bfloat16* __restrict__ k_sd,
    const __hip_bfloat16* __restrict__ v_ds, float* __restrict__ y) {
  __shared__ __align__(16) char K_lds[2][8192];
  __shared__ __align__(16) char V_lds[2][8192];
  __shared__ __align__(16) unsigned short Ps[4][32][72];  // per-wave P rows
  int t = threadIdx.x;
  int w = t >> 6, l = t & 63;
  int l15 = l & 15, lg = l >> 4;
  int qb = blockIdx.x, bn = blockIdx.y;
  const char* qg = (const char*)(q_sd + (size_t)bn * 65536);   // [s][d]
  const char* kg = (const char*)(k_sd + (size_t)bn * 65536);   // [s][d]
  const char* vg = (const char*)(v_ds + (size_t)bn * 65536);   // [d][s]

  // Q B-fragments, held in registers for the whole block.
  // B-frag: col = l&15 = q(within subtile), k = lg*8+e = d.
  short8 bq[2][2];
  int qrow_base = qb * 128 + w * 32;
#pragma unroll
  for (int c = 0; c < 2; ++c)
#pragma unroll
    for (int h = 0; h < 2; ++h)
      bq[c][h] = *(const short8*)(qg +
          2 * ((size_t)(qrow_base + c * 16 + l15) * 64 + h * 32 + lg * 8));

  f32x4 o_acc[4][2];
#pragma unroll
  for (int dt = 0; dt < 4; ++dt)
#pragma unroll
    for (int c = 0; c < 2; ++c) o_acc[dt][c] = (f32x4){0.f, 0.f, 0.f, 0.f};
  float m_run[2] = {-1e30f, -1e30f}, l_run[2] = {0.f, 0.f};

  int row = t >> 2;               // staging row 0..63
  int coff = (t & 3) * 32;        // byte offset within 128B row
  int swr = (row & 7) << 4;
  // prologue: stage tile 0 into buffer 0
  {
    const char* ksrc = kg + (size_t)t * 32;
    const char* vsrc = vg + (size_t)row * 2048 + coff;
    uint4 a = *(const uint4*)(ksrc);
    uint4 b2 = *(const uint4*)(ksrc + 16);
    uint4 c2 = *(const uint4*)(vsrc);
    uint4 d2 = *(const uint4*)(vsrc + 16);
    *(uint4*)(K_lds[0] + ((t * 32) ^ swr)) = a;
    *(uint4*)(K_lds[0] + ((t * 32 + 16) ^ swr)) = b2;
    *(uint4*)(V_lds[0] + ((t * 32) ^ swr)) = c2;
    *(uint4*)(V_lds[0] + ((t * 32 + 16) ^ swr)) = d2;
  }
  __syncthreads();

  for (int kb = 0; kb < 16; ++kb) {
    int buf = kb & 1;
    uint4 pk0, pk1, pk2, pk3;
    if (kb < 15) {  // issue next-tile loads early (hide HBM under MFMA)
      const char* ksrc = kg + (size_t)(kb + 1) * 8192 + (size_t)t * 32;
      const char* vsrc = vg + (size_t)row * 2048 + (size_t)(kb + 1) * 128 + coff;
      pk0 = *(const uint4*)(ksrc);
      pk1 = *(const uint4*)(ksrc + 16);
      pk2 = *(const uint4*)(vsrc);
      pk3 = *(const uint4*)(vsrc + 16);
    }
    // ---- S^T = K · Q^T : A-frag row = key, k = d
    short8 a_k[4][2];
#pragma unroll
    for (int kt = 0; kt < 4; ++kt) {
      int key = kt * 16 + l15;
      int sw = (key & 7) << 4;
#pragma unroll
      for (int h = 0; h < 2; ++h)
        a_k[kt][h] = *(const short8*)(K_lds[buf] +
            ((key * 128 + h * 64 + lg * 16) ^ sw));
    }
    f32x4 s_acc[4][2];
#pragma unroll
    for (int kt = 0; kt < 4; ++kt)
#pragma unroll
      for (int c = 0; c < 2; ++c) {
        f32x4 acc = (f32x4){0.f, 0.f, 0.f, 0.f};
        acc = __builtin_amdgcn_mfma_f32_16x16x32_bf16(a_k[kt][0], bq[c][0], acc, 0, 0, 0);
        acc = __builtin_amdgcn_mfma_f32_16x16x32_bf16(a_k[kt][1], bq[c][1], acc, 0, 0, 0);
        s_acc[kt][c] = acc;
      }
    // ---- online softmax per q-subtile (values are ln2-scaled; exp2 native)
#pragma unroll
    for (int c = 0; c < 2; ++c) {
      float mt = -1e30f;
#pragma unroll
      for (int kt = 0; kt < 4; ++kt)
#pragma unroll
        for (int r = 0; r < 4; ++r) mt = fmaxf(mt, s_acc[kt][c][r]);
      mt = fmaxf(mt, __shfl_xor(mt, 16, 64));
      mt = fmaxf(mt, __shfl_xor(mt, 32, 64));
      float m_new = fmaxf(m_run[c], mt);
      float fsc = exp2f(m_run[c] - m_new);
      m_run[c] = m_new;
      float ts = 0.f;
#pragma unroll
      for (int kt = 0; kt < 4; ++kt) {
        float p0 = exp2f(s_acc[kt][c][0] - m_new);
        float p1 = exp2f(s_acc[kt][c][1] - m_new);
        float p2 = exp2f(s_acc[kt][c][2] - m_new);
        float p3 = exp2f(s_acc[kt][c][3] - m_new);
        ts += (p0 + p1) + (p2 + p3);
        uint2 pr;
        pr.x = (unsigned)f2bf(p0) | ((unsigned)f2bf(p1) << 16);
        pr.y = (unsigned)f2bf(p2) | ((unsigned)f2bf(p3) << 16);
        *(uint2*)&Ps[w][c * 16 + l15][kt * 16 + lg * 4] = pr;
      }
      ts += __shfl_xor(ts, 16, 64);
      ts += __shfl_xor(ts, 32, 64);
      l_run[c] = l_run[c] * fsc + ts;
#pragma unroll
      for (int dt = 0; dt < 4; ++dt)
#pragma unroll
        for (int r = 0; r < 4; ++r) o_acc[dt][c][r] *= fsc;
    }
    // ---- O^T += V^T · P^T : A-frag row = d, k = key
    short8 a_v[4][2];
#pragma unroll
    for (int dt = 0; dt < 4; ++dt) {
      int d = dt * 16 + l15;
      int sw = (d & 7) << 4;
#pragma unroll
      for (int h = 0; h < 2; ++h)
        a_v[dt][h] = *(const short8*)(V_lds[buf] +
            ((d * 128 + h * 64 + lg * 16) ^ sw));
    }
    short8 pbf[2][2];
#pragma unroll
    for (int c = 0; c < 2; ++c)
#pragma unroll
      for (int h = 0; h < 2; ++h)
        pbf[c][h] = *(const short8*)((const char*)&Ps[w][c * 16 + l15][0] +
            (lg * 8 + h * 32) * 2);
#pragma unroll
    for (int dt = 0; dt < 4; ++dt)
#pragma unroll
      for (int c = 0; c < 2; ++c) {
        o_acc[dt][c] = __builtin_amdgcn_mfma_f32_16x16x32_bf16(a_v[dt][0], pbf[c][0], o_acc[dt][c], 0, 0, 0);
        o_acc[dt][c] = __builtin_amdgcn_mfma_f32_16x16x32_bf16(a_v[dt][1], pbf[c][1], o_acc[dt][c], 0, 0, 0);
      }
    // ---- write next tile into the other buffer, single barrier
    if (kb < 15) {
      int nb = buf ^ 1;
      *(uint4*)(K_lds[nb] + ((t * 32) ^ swr)) = pk0;
      *(uint4*)(K_lds[nb] + ((t * 32 + 16) ^ swr)) = pk1;
      *(uint4*)(V_lds[nb] + ((t * 32) ^ swr)) = pk2;
      *(uint4*)(V_lds[nb] + ((t * 32 + 16) ^ swr)) = pk3;
    }
    __syncthreads();
  }
  // ---- epilogue: O^T is already [d][q] = proj-GEMM layout
  int b_ = bn >> 3, n_ = bn & 7;
#pragma unroll
  for (int c = 0; c < 2; ++c) {
    float invl = 1.0f / l_run[c];
    int q = qb * 128 + w * 32 + c * 16 + l15;
#pragma unroll
    for (int dt = 0; dt < 4; ++dt)
#pragma unroll
      for (int r = 0; r < 4; ++r) {
        int d = dt * 16 + lg * 4 + r;
        y[((size_t)(b_ * 512 + n_ * 64 + d)) * 1024 + q] = o_acc[dt][c][r] * invl;
      }
  }
}

// ---------------------------------------------------------------------------
extern "C" void kernel_launch(void* const* d_in, const int* in_sizes, int n_in,
                              void* d_out, int out_size, void* d_ws, size_t ws_size,
                              hipStream_t stream) {
  const float* x      = (const float*)d_in[0];  // [16][512][1024]
  const float* w_attn = (const float*)d_in[1];  // [1536][512]
  const float* w_proj = (const float*)d_in[2];  // [512][512]
  float* out = (float*)d_out;

  float* ws = (float*)d_ws;
  float* wn_attn = ws;                                   // 786432 f32
  float* wn_proj = wn_attn + 786432;                     // 262144 f32
  float* xp = wn_proj + 262144;                          // 25165824 f32
  float* y  = xp;  // alias: attn writes y after xp's last read (repack_qk)
  float* f  = xp + 25165824;                             // 2097152 f32
  __hip_bfloat16* q_sd = (__hip_bfloat16*)(f + 2097152); // 8388608 bf16
  __hip_bfloat16* k_sd = q_sd + 8388608;
  __hip_bfloat16* v_ds = k_sd + 8388608;

  wnorm_kernel<<<dim3(2048), dim3(256), 0, stream>>>(w_attn, w_proj, wn_attn, wn_proj);
  gemm_kernel<0><<<dim3(16, 24, 16), dim3(256), 0, stream>>>(
      wn_attn, x, xp, nullptr, 1536, 512, 1024);
  scale_v_kernel<<<dim3(12288), dim3(256), 0, stream>>>(xp, f, v_ds);
  repack_qk<<<dim3(16, 8, 32), dim3(256), 0, stream>>>(xp, f, q_sd, k_sd);
  attn_mfma<<<dim3(8, 128), dim3(256), 0, stream>>>(q_sd, k_sd, v_ds, y);
  gemm_kernel<1><<<dim3(16, 8, 16), dim3(256), 0, stream>>>(
      wn_proj, y, out, x, 512, 512, 1024);
}

// Round 3
// 191.040 us; speedup vs baseline: 11.8737x; 4.0384x over previous
//
#include <hip/hip_runtime.h>
#include <hip/hip_bf16.h>

// ---------------------------------------------------------------------------
// CosineAttention forward.  b=16, c=512, h=w=32 -> seq=1024, heads=8, hd=64.
//
// Pipeline (all matmuls bf16 MFMA 16x16x32, fp32 accumulate):
//  1) wnorm_kernel   : normalized bf16 w_attn (1536x512), w_proj (512x512)
//  2) xt_kernel      : x fp32 [b][c][s] -> x_t bf16 [b][s][c]
//  3) gemm_bf16<0>   : xp[b][1536][1024] fp32 = wn_attn @ x   (B = x_t)
//  4) scale_v_kernel : heads-axis pixel_norm scale f; emits V bf16 [bn][d][s]
//  5) repack_qk      : Q,K bf16 [bn][s][d]; Q gets 0.125*log2(e) folded
//  6) attn_mfma      : flash attention, writes y_t bf16 [b][s][ch]
//  7) gemm_bf16<1>   : out = mp_add(x, wn_proj @ y)           (B = y_t)
// ---------------------------------------------------------------------------

typedef __attribute__((ext_vector_type(8))) short short8;
typedef __attribute__((ext_vector_type(4))) float f32x4;

__device__ inline unsigned short f2bf(float v) {
  __hip_bfloat16 h = __float2bfloat16(v);
  return *reinterpret_cast<unsigned short*>(&h);
}

__device__ inline void gload16(const void* g, void* l) {
  __builtin_amdgcn_global_load_lds(
      (const __attribute__((address_space(1))) unsigned int*)g,
      (__attribute__((address_space(3))) unsigned int*)l, 16, 0, 0);
}

// ---------------- weight normalization (bf16 out) --------------------------
__global__ __launch_bounds__(256) void wnorm_kernel(
    const float* __restrict__ wa, const float* __restrict__ wp,
    __hip_bfloat16* __restrict__ wna, __hip_bfloat16* __restrict__ wnp) {
  int o = blockIdx.x;
  const float* src;
  __hip_bfloat16* dst;
  if (o < 1536) { src = wa + (size_t)o * 512; dst = wna + (size_t)o * 512; }
  else          { src = wp + (size_t)(o - 1536) * 512; dst = wnp + (size_t)(o - 1536) * 512; }
  int tid = threadIdx.x;
  float a = src[tid], b = src[tid + 256];
  float ss = a * a + b * b;
#pragma unroll
  for (int off = 32; off > 0; off >>= 1) ss += __shfl_down(ss, off, 64);
  __shared__ float wsum[4];
  if ((tid & 63) == 0) wsum[tid >> 6] = ss;
  __syncthreads();
  float tot = wsum[0] + wsum[1] + wsum[2] + wsum[3];
  float r = 1.0f / (sqrtf(tot) + 2.2627416997969522e-3f);  // n + EPS*sqrt(512)
  dst[tid] = __float2bfloat16(a * r);
  dst[tid + 256] = __float2bfloat16(b * r);
}

// ---------------- x -> bf16 [b][s][c] transpose ----------------------------
__global__ __launch_bounds__(256) void xt_kernel(
    const float* __restrict__ x, __hip_bfloat16* __restrict__ xt) {
  __shared__ __align__(16) unsigned short trans[64][68];
  int s0 = blockIdx.x * 64, c0 = blockIdx.y * 64, b = blockIdx.z;
  int t = threadIdx.x;
  int sl = t & 63, cg = t >> 6;
  const float* src = x + (size_t)b * 524288 + (size_t)(c0 + cg * 16) * 1024 + s0 + sl;
#pragma unroll
  for (int i = 0; i < 16; i += 2) {
    float v0 = src[(size_t)i * 1024];
    float v1 = src[(size_t)(i + 1) * 1024];
    *(unsigned*)&trans[sl][cg * 16 + i] = (unsigned)f2bf(v0) | ((unsigned)f2bf(v1) << 16);
  }
  __syncthreads();
  int sw = t >> 2, cw = (t & 3) * 16;
  __hip_bfloat16* dst = xt + (size_t)b * 524288 + (size_t)(s0 + sw) * 512 + c0 + cw;
  uint2 r0 = *(uint2*)&trans[sw][cw + 0];
  uint2 r1 = *(uint2*)&trans[sw][cw + 4];
  uint2 r2 = *(uint2*)&trans[sw][cw + 8];
  uint2 r3 = *(uint2*)&trans[sw][cw + 12];
  uint4 o0 = {r0.x, r0.y, r1.x, r1.y};
  uint4 o1 = {r2.x, r2.y, r3.x, r3.y};
  *(uint4*)dst = o0;
  *(uint4*)((char*)dst + 16) = o1;
}

// ---------------- bf16 MFMA GEMM:  Out[b][M][1024] = A[Mx512] @ B[b]^T -----
// A: bf16 [M][512] row-major (k-contiguous).  B: bf16 [b][1024][512]
// (k-contiguous; logical B[k][n] = Bmem[n][k]).  Out fp32.
// EPI=1: Out = 0.9191450*resid + 0.3939193*Out  (mp_add t=0.3)
// 128x128 tile, BK=64, 4 waves (2x2), global_load_lds + XOR-swizzled source.
template <int EPI>
__global__ __launch_bounds__(256) void gemm_bf16(
    const __hip_bfloat16* __restrict__ A, const __hip_bfloat16* __restrict__ B,
    float* __restrict__ Out, const float* __restrict__ resid, int M) {
  __shared__ __align__(16) char Al[2][16384];
  __shared__ __align__(16) char Bl[2][16384];
  int t = threadIdx.x;
  int w = t >> 6, l = t & 63;
  int l15 = l & 15, lg = l >> 4;
  int wm = w >> 1, wn = w & 1;
  int n0 = blockIdx.x * 128, m0 = blockIdx.y * 128, b = blockIdx.z;
  const char* Ab = (const char*)A + (size_t)m0 * 1024;
  const char* Bb = (const char*)B + (size_t)b * 1048576 + (size_t)n0 * 1024;
  // staging geometry: LDS addr a = i*4096 + t*16 holds tile row a>>7 at
  // logical byte (a&127); source pre-swizzled so reads XOR the same pattern.
  int rl = t >> 3;                                        // row 0..31 (+32i)
  int soff = ((t & 7) * 16) ^ ((rl & 7) << 4);
  const char* asrc = Ab + (size_t)rl * 1024 + soff;
  const char* bsrc = Bb + (size_t)rl * 1024 + soff;

#define STAGE(bi, k0b)                                                    \
  do {                                                                    \
    _Pragma("unroll") for (int i = 0; i < 4; ++i) {                       \
      gload16(asrc + (size_t)i * 32768 + (k0b), Al[bi] + i * 4096 + w * 1024); \
      gload16(bsrc + (size_t)i * 32768 + (k0b), Bl[bi] + i * 4096 + w * 1024); \
    }                                                                     \
  } while (0)

  f32x4 acc[4][4];
#pragma unroll
  for (int mi = 0; mi < 4; ++mi)
#pragma unroll
    for (int ni = 0; ni < 4; ++ni) acc[mi][ni] = (f32x4){0.f, 0.f, 0.f, 0.f};

  STAGE(0, 0);
  __syncthreads();

  for (int ks = 0; ks < 8; ++ks) {
    int buf = ks & 1;
    if (ks < 7) STAGE(buf ^ 1, (ks + 1) * 128);
    short8 af[4][2], bf[4][2];
#pragma unroll
    for (int mi = 0; mi < 4; ++mi) {
      int row = wm * 64 + mi * 16 + l15;
      int sw = (row & 7) << 4;
#pragma unroll
      for (int h = 0; h < 2; ++h)
        af[mi][h] = *(const short8*)(Al[buf] + row * 128 + ((h * 64 + lg * 16) ^ sw));
    }
#pragma unroll
    for (int ni = 0; ni < 4; ++ni) {
      int row = wn * 64 + ni * 16 + l15;
      int sw = (row & 7) << 4;
#pragma unroll
      for (int h = 0; h < 2; ++h)
        bf[ni][h] = *(const short8*)(Bl[buf] + row * 128 + ((h * 64 + lg * 16) ^ sw));
    }
#pragma unroll
    for (int mi = 0; mi < 4; ++mi)
#pragma unroll
      for (int ni = 0; ni < 4; ++ni) {
        acc[mi][ni] = __builtin_amdgcn_mfma_f32_16x16x32_bf16(af[mi][0], bf[ni][0], acc[mi][ni], 0, 0, 0);
        acc[mi][ni] = __builtin_amdgcn_mfma_f32_16x16x32_bf16(af[mi][1], bf[ni][1], acc[mi][ni], 0, 0, 0);
      }
    if (ks < 7) __syncthreads();
  }
#undef STAGE

  float* outb = Out + (size_t)b * M * 1024;
  const float* rb = resid + (size_t)b * M * 1024;
#pragma unroll
  for (int mi = 0; mi < 4; ++mi) {
    int row = m0 + wm * 64 + mi * 16 + lg * 4;
#pragma unroll
    for (int r = 0; r < 4; ++r) {
      float* orow = outb + (size_t)(row + r) * 1024 + n0 + wn * 64 + l15;
#pragma unroll
      for (int ni = 0; ni < 4; ++ni) {
        float v = acc[mi][ni][r];
        if (EPI) {
          const float* rrow = rb + (size_t)(row + r) * 1024 + n0 + wn * 64 + l15;
          v = 0.9191450300180578f * rrow[ni * 16] + 0.39391929857916763f * v;
        }
        orow[ni * 16] = v;
      }
    }
  }
}

// ---------------- scale (pixel_norm over heads) + V emit -------------------
__global__ __launch_bounds__(256) void scale_v_kernel(
    const float* __restrict__ xp, float* __restrict__ f,
    __hip_bfloat16* __restrict__ v_ds) {
  size_t id = (size_t)blockIdx.x * 256 + threadIdx.x;  // 16*3*64*1024
  int s = id & 1023;
  int d = (int)((id >> 10) & 63);
  int gb = (int)(id >> 16);
  int g = gb % 3, b = gb / 3;
  const float* base = xp + ((size_t)(b * 1536 + g * 512 + d) * 1024 + s);
  float v[8];
  float ss = 0.f;
#pragma unroll
  for (int n = 0; n < 8; ++n) {
    v[n] = base[(size_t)n * 65536];
    ss += v[n] * v[n];
  }
  float fv = rsqrtf(ss * 0.125f + 1e-4f);
  if (g == 2) {
#pragma unroll
    for (int n = 0; n < 8; ++n)
      v_ds[((size_t)((b * 8 + n) * 64 + d)) * 1024 + s] = __float2bfloat16(v[n] * fv);
  } else {
    f[((size_t)((b * 2 + g) * 64 + d)) * 1024 + s] = fv;
  }
}

// ---------------- repack Q,K to seq-major bf16 [bn][s][d] ------------------
__global__ __launch_bounds__(256) void repack_qk(
    const float* __restrict__ xp, const float* __restrict__ f,
    __hip_bfloat16* __restrict__ q_sd, __hip_bfloat16* __restrict__ k_sd) {
  __shared__ __align__(16) unsigned short trans[64][68];
  int s0 = blockIdx.x * 64;
  int n = blockIdx.y;
  int g = blockIdx.z & 1, b = blockIdx.z >> 1;
  int t = threadIdx.x;
  int sl = t & 63, dg = t >> 6;
  const float* src = xp + ((size_t)(b * 1536 + g * 512 + n * 64 + dg * 16) * 1024) + s0 + sl;
  const float* fs = f + ((size_t)((b * 2 + g) * 64 + dg * 16) * 1024) + s0 + sl;
  float qm = g ? 1.0f : 0.18033688011112042f;  // 0.125 * log2(e) folded into Q
#pragma unroll
  for (int i = 0; i < 16; i += 2) {
    float v0 = src[(size_t)i * 1024] * (fs[(size_t)i * 1024] * qm);
    float v1 = src[(size_t)(i + 1) * 1024] * (fs[(size_t)(i + 1) * 1024] * qm);
    *(unsigned*)&trans[sl][dg * 16 + i] = (unsigned)f2bf(v0) | ((unsigned)f2bf(v1) << 16);
  }
  __syncthreads();
  int sw = t >> 2, dw = (t & 3) * 16;
  uint2 r0 = *(uint2*)&trans[sw][dw + 0];
  uint2 r1 = *(uint2*)&trans[sw][dw + 4];
  uint2 r2 = *(uint2*)&trans[sw][dw + 8];
  uint2 r3 = *(uint2*)&trans[sw][dw + 12];
  __hip_bfloat16* dst = (g ? k_sd : q_sd) +
      ((size_t)((b * 8 + n) * 1024 + s0 + sw) * 64 + dw);
  uint4 o0 = {r0.x, r0.y, r1.x, r1.y};
  uint4 o1 = {r2.x, r2.y, r3.x, r3.y};
  *(uint4*)dst = o0;
  *(uint4*)((char*)dst + 16) = o1;
}

// ---------------- flash attention, bf16 MFMA -------------------------------
// Grid (qb=8 [128 q each], bn=128). 4 waves; wave w owns 32 q (2 subtiles).
// Swapped operands: S^T = mfma(K, Q^T), O^T = mfma(V^T, P^T).
// Writes y_t bf16 [b][s][ch]  (proj-GEMM B layout).
__global__ __launch_bounds__(256) void attn_mfma(
    const __hip_bfloat16* __restrict__ q_sd, const __hip_bfloat16* __restrict__ k_sd,
    const __hip_bfloat16* __restrict__ v_ds, __hip_bfloat16* __restrict__ y_t) {
  __shared__ __align__(16) char K_lds[2][8192];
  __shared__ __align__(16) char V_lds[2][8192];
  __shared__ __align__(16) unsigned short Ps[4][32][72];
  int t = threadIdx.x;
  int w = t >> 6, l = t & 63;
  int l15 = l & 15, lg = l >> 4;
  int qb = blockIdx.x, bn = blockIdx.y;
  const char* qg = (const char*)(q_sd + (size_t)bn * 65536);   // [s][d]
  const char* kg = (const char*)(k_sd + (size_t)bn * 65536);   // [s][d]
  const char* vg = (const char*)(v_ds + (size_t)bn * 65536);   // [d][s]

  short8 bq[2][2];
  int qrow_base = qb * 128 + w * 32;
#pragma unroll
  for (int c = 0; c < 2; ++c)
#pragma unroll
    for (int h = 0; h < 2; ++h)
      bq[c][h] = *(const short8*)(qg +
          2 * ((size_t)(qrow_base + c * 16 + l15) * 64 + h * 32 + lg * 8));

  f32x4 o_acc[4][2];
#pragma unroll
  for (int dt = 0; dt < 4; ++dt)
#pragma unroll
    for (int c = 0; c < 2; ++c) o_acc[dt][c] = (f32x4){0.f, 0.f, 0.f, 0.f};
  float m_run[2] = {-1e30f, -1e30f}, l_run[2] = {0.f, 0.f};

  int row = t >> 2;
  int coff = (t & 3) * 32;
  int swr = (row & 7) << 4;
  {
    const char* ksrc = kg + (size_t)t * 32;
    const char* vsrc = vg + (size_t)row * 2048 + coff;
    uint4 a = *(const uint4*)(ksrc);
    uint4 b2 = *(const uint4*)(ksrc + 16);
    uint4 c2 = *(const uint4*)(vsrc);
    uint4 d2 = *(const uint4*)(vsrc + 16);
    *(uint4*)(K_lds[0] + ((t * 32) ^ swr)) = a;
    *(uint4*)(K_lds[0] + ((t * 32 + 16) ^ swr)) = b2;
    *(uint4*)(V_lds[0] + ((t * 32) ^ swr)) = c2;
    *(uint4*)(V_lds[0] + ((t * 32 + 16) ^ swr)) = d2;
  }
  __syncthreads();

  for (int kb = 0; kb < 16; ++kb) {
    int buf = kb & 1;
    uint4 pk0, pk1, pk2, pk3;
    if (kb < 15) {
      const char* ksrc = kg + (size_t)(kb + 1) * 8192 + (size_t)t * 32;
      const char* vsrc = vg + (size_t)row * 2048 + (size_t)(kb + 1) * 128 + coff;
      pk0 = *(const uint4*)(ksrc);
      pk1 = *(const uint4*)(ksrc + 16);
      pk2 = *(const uint4*)(vsrc);
      pk3 = *(const uint4*)(vsrc + 16);
    }
    short8 a_k[4][2];
#pragma unroll
    for (int kt = 0; kt < 4; ++kt) {
      int key = kt * 16 + l15;
      int sw = (key & 7) << 4;
#pragma unroll
      for (int h = 0; h < 2; ++h)
        a_k[kt][h] = *(const short8*)(K_lds[buf] + ((key * 128 + h * 64 + lg * 16) ^ sw));
    }
    f32x4 s_acc[4][2];
#pragma unroll
    for (int kt = 0; kt < 4; ++kt)
#pragma unroll
      for (int c = 0; c < 2; ++c) {
        f32x4 acc = (f32x4){0.f, 0.f, 0.f, 0.f};
        acc = __builtin_amdgcn_mfma_f32_16x16x32_bf16(a_k[kt][0], bq[c][0], acc, 0, 0, 0);
        acc = __builtin_amdgcn_mfma_f32_16x16x32_bf16(a_k[kt][1], bq[c][1], acc, 0, 0, 0);
        s_acc[kt][c] = acc;
      }
#pragma unroll
    for (int c = 0; c < 2; ++c) {
      float mt = -1e30f;
#pragma unroll
      for (int kt = 0; kt < 4; ++kt)
#pragma unroll
        for (int r = 0; r < 4; ++r) mt = fmaxf(mt, s_acc[kt][c][r]);
      mt = fmaxf(mt, __shfl_xor(mt, 16, 64));
      mt = fmaxf(mt, __shfl_xor(mt, 32, 64));
      float m_new = fmaxf(m_run[c], mt);
      float fsc = exp2f(m_run[c] - m_new);
      m_run[c] = m_new;
      float ts = 0.f;
#pragma unroll
      for (int kt = 0; kt < 4; ++kt) {
        float p0 = exp2f(s_acc[kt][c][0] - m_new);
        float p1 = exp2f(s_acc[kt][c][1] - m_new);
        float p2 = exp2f(s_acc[kt][c][2] - m_new);
        float p3 = exp2f(s_acc[kt][c][3] - m_new);
        ts += (p0 + p1) + (p2 + p3);
        uint2 pr;
        pr.x = (unsigned)f2bf(p0) | ((unsigned)f2bf(p1) << 16);
        pr.y = (unsigned)f2bf(p2) | ((unsigned)f2bf(p3) << 16);
        *(uint2*)&Ps[w][c * 16 + l15][kt * 16 + lg * 4] = pr;
      }
      ts += __shfl_xor(ts, 16, 64);
      ts += __shfl_xor(ts, 32, 64);
      l_run[c] = l_run[c] * fsc + ts;
#pragma unroll
      for (int dt = 0; dt < 4; ++dt)
#pragma unroll
        for (int r = 0; r < 4; ++r) o_acc[dt][c][r] *= fsc;
    }
    short8 a_v[4][2];
#pragma unroll
    for (int dt = 0; dt < 4; ++dt) {
      int d = dt * 16 + l15;
      int sw = (d & 7) << 4;
#pragma unroll
      for (int h = 0; h < 2; ++h)
        a_v[dt][h] = *(const short8*)(V_lds[buf] + ((d * 128 + h * 64 + lg * 16) ^ sw));
    }
    short8 pbf[2][2];
#pragma unroll
    for (int c = 0; c < 2; ++c)
#pragma unroll
      for (int h = 0; h < 2; ++h)
        pbf[c][h] = *(const short8*)((const char*)&Ps[w][c * 16 + l15][0] + (lg * 8 + h * 32) * 2);
#pragma unroll
    for (int dt = 0; dt < 4; ++dt)
#pragma unroll
      for (int c = 0; c < 2; ++c) {
        o_acc[dt][c] = __builtin_amdgcn_mfma_f32_16x16x32_bf16(a_v[dt][0], pbf[c][0], o_acc[dt][c], 0, 0, 0);
        o_acc[dt][c] = __builtin_amdgcn_mfma_f32_16x16x32_bf16(a_v[dt][1], pbf[c][1], o_acc[dt][c], 0, 0, 0);
      }
    if (kb < 15) {
      int nb = buf ^ 1;
      *(uint4*)(K_lds[nb] + ((t * 32) ^ swr)) = pk0;
      *(uint4*)(K_lds[nb] + ((t * 32 + 16) ^ swr)) = pk1;
      *(uint4*)(V_lds[nb] + ((t * 32) ^ swr)) = pk2;
      *(uint4*)(V_lds[nb] + ((t * 32 + 16) ^ swr)) = pk3;
    }
    __syncthreads();
  }
  // epilogue: y_t[b][s=q][ch = n*64+d], 4 consecutive d per lane -> 8B store
  int b_ = bn >> 3, n_ = bn & 7;
#pragma unroll
  for (int c = 0; c < 2; ++c) {
    float invl = 1.0f / l_run[c];
    int q = qb * 128 + w * 32 + c * 16 + l15;
    __hip_bfloat16* yrow = y_t + (size_t)b_ * 524288 + (size_t)q * 512 + n_ * 64 + lg * 4;
#pragma unroll
    for (int dt = 0; dt < 4; ++dt) {
      uint2 pr;
      pr.x = (unsigned)f2bf(o_acc[dt][c][0] * invl) | ((unsigned)f2bf(o_acc[dt][c][1] * invl) << 16);
      pr.y = (unsigned)f2bf(o_acc[dt][c][2] * invl) | ((unsigned)f2bf(o_acc[dt][c][3] * invl) << 16);
      *(uint2*)(yrow + dt * 16) = pr;
    }
  }
}

// ---------------------------------------------------------------------------
extern "C" void kernel_launch(void* const* d_in, const int* in_sizes, int n_in,
                              void* d_out, int out_size, void* d_ws, size_t ws_size,
                              hipStream_t stream) {
  const float* x      = (const float*)d_in[0];  // [16][512][1024]
  const float* w_attn = (const float*)d_in[1];  // [1536][512]
  const float* w_proj = (const float*)d_in[2];  // [512][512]
  float* out = (float*)d_out;

  // workspace layout (~161 MB)
  __hip_bfloat16* wn_attn = (__hip_bfloat16*)d_ws;        // 1536*512
  __hip_bfloat16* wn_proj = wn_attn + 786432;             // 512*512
  __hip_bfloat16* x_t     = wn_proj + 262144;             // 16*1024*512
  __hip_bfloat16* v_ds    = x_t;                          // alias (x_t dead after gemm<0>)
  float* xp = (float*)(x_t + 8388608);                    // 16*1536*1024 f32
  __hip_bfloat16* y_t = (__hip_bfloat16*)xp;              // alias (xp dead after repack)
  float* f = xp + 25165824;                               // 16*2*64*1024 f32
  __hip_bfloat16* q_sd = (__hip_bfloat16*)(f + 2097152);  // 16*8*1024*64
  __hip_bfloat16* k_sd = q_sd + 8388608;

  wnorm_kernel<<<dim3(2048), dim3(256), 0, stream>>>(w_attn, w_proj, wn_attn, wn_proj);
  xt_kernel<<<dim3(16, 8, 16), dim3(256), 0, stream>>>(x, x_t);
  gemm_bf16<0><<<dim3(8, 12, 16), dim3(256), 0, stream>>>(wn_attn, x_t, xp, nullptr, 1536);
  scale_v_kernel<<<dim3(12288), dim3(256), 0, stream>>>(xp, f, v_ds);
  repack_qk<<<dim3(16, 8, 32), dim3(256), 0, stream>>>(xp, f, q_sd, k_sd);
  attn_mfma<<<dim3(8, 128), dim3(256), 0, stream>>>(q_sd, k_sd, v_ds, y_t);
  gemm_bf16<1><<<dim3(8, 4, 16), dim3(256), 0, stream>>>(wn_proj, y_t, out, x, 512);
}

// Round 4
// 174.539 us; speedup vs baseline: 12.9963x; 1.0945x over previous
//
#include <hip/hip_runtime.h>
#include <hip/hip_bf16.h>

// ---------------------------------------------------------------------------
// CosineAttention forward.  b=16, c=512, h=w=32 -> seq=1024, heads=8, hd=64.
//
// Pipeline (all matmuls bf16 MFMA 16x16x32, fp32 accumulate):
//  1) wnorm_kernel : normalized bf16 w_attn (1536x512), w_proj (512x512)
//  2) xt_kernel    : x fp32 [b][c][s] -> x_t bf16 [b][s][c]
//  3) gemm_bf16<0> : xp[b][1536][1024] bf16 = wn_attn @ x   (B = x_t)
//  4) norm_pack    : fused pixel_norm + repack: q_sd,k_sd bf16 [bn][s][d]
//                    (Q gets 0.125*log2e), v_ds bf16 [bn][d][s]
//  5) attn_mfma    : flash attention (defer-max, cvt_pk, setprio, XCD-local
//                    grid), writes y_t bf16 [b][s][ch]
//  6) gemm_bf16<1> : out = mp_add(x, wn_proj @ y)           (B = y_t)
// ---------------------------------------------------------------------------

typedef __attribute__((ext_vector_type(8))) short short8;
typedef __attribute__((ext_vector_type(4))) float f32x4;
typedef __attribute__((ext_vector_type(4))) unsigned short ushort4_t;

__device__ inline unsigned short f2bf(float v) {
  __hip_bfloat16 h = __float2bfloat16(v);
  return *reinterpret_cast<unsigned short*>(&h);
}
__device__ inline float bf2f(unsigned short u) {
  return __uint_as_float((unsigned)u << 16);
}
__device__ inline unsigned cvt_pk(float lo, float hi) {
  unsigned r;
  asm("v_cvt_pk_bf16_f32 %0, %1, %2" : "=v"(r) : "v"(lo), "v"(hi));
  return r;
}
__device__ inline void gload16(const void* g, void* l) {
  __builtin_amdgcn_global_load_lds(
      (const __attribute__((address_space(1))) unsigned int*)g,
      (__attribute__((address_space(3))) unsigned int*)l, 16, 0, 0);
}

// ---------------- weight normalization (bf16 out) --------------------------
__global__ __launch_bounds__(256) void wnorm_kernel(
    const float* __restrict__ wa, const float* __restrict__ wp,
    __hip_bfloat16* __restrict__ wna, __hip_bfloat16* __restrict__ wnp) {
  int o = blockIdx.x;
  const float* src;
  __hip_bfloat16* dst;
  if (o < 1536) { src = wa + (size_t)o * 512; dst = wna + (size_t)o * 512; }
  else          { src = wp + (size_t)(o - 1536) * 512; dst = wnp + (size_t)(o - 1536) * 512; }
  int tid = threadIdx.x;
  float a = src[tid], b = src[tid + 256];
  float ss = a * a + b * b;
#pragma unroll
  for (int off = 32; off > 0; off >>= 1) ss += __shfl_down(ss, off, 64);
  __shared__ float wsum[4];
  if ((tid & 63) == 0) wsum[tid >> 6] = ss;
  __syncthreads();
  float tot = wsum[0] + wsum[1] + wsum[2] + wsum[3];
  float r = 1.0f / (sqrtf(tot) + 2.2627416997969522e-3f);  // n + EPS*sqrt(512)
  dst[tid] = __float2bfloat16(a * r);
  dst[tid + 256] = __float2bfloat16(b * r);
}

// ---------------- x -> bf16 [b][s][c] transpose ----------------------------
__global__ __launch_bounds__(256) void xt_kernel(
    const float* __restrict__ x, __hip_bfloat16* __restrict__ xt) {
  __shared__ __align__(16) unsigned short trans[64][68];
  int s0 = blockIdx.x * 64, c0 = blockIdx.y * 64, b = blockIdx.z;
  int t = threadIdx.x;
  int sl = t & 63, cg = t >> 6;
  const float* src = x + (size_t)b * 524288 + (size_t)(c0 + cg * 16) * 1024 + s0 + sl;
#pragma unroll
  for (int i = 0; i < 16; i += 2) {
    float v0 = src[(size_t)i * 1024];
    float v1 = src[(size_t)(i + 1) * 1024];
    *(unsigned*)&trans[sl][cg * 16 + i] = (unsigned)f2bf(v0) | ((unsigned)f2bf(v1) << 16);
  }
  __syncthreads();
  int sw = t >> 2, cw = (t & 3) * 16;
  __hip_bfloat16* dst = xt + (size_t)b * 524288 + (size_t)(s0 + sw) * 512 + c0 + cw;
  uint2 r0 = *(uint2*)&trans[sw][cw + 0];
  uint2 r1 = *(uint2*)&trans[sw][cw + 4];
  uint2 r2 = *(uint2*)&trans[sw][cw + 8];
  uint2 r3 = *(uint2*)&trans[sw][cw + 12];
  uint4 o0 = {r0.x, r0.y, r1.x, r1.y};
  uint4 o1 = {r2.x, r2.y, r3.x, r3.y};
  *(uint4*)dst = o0;
  *(uint4*)((char*)dst + 16) = o1;
}

// ---------------- bf16 MFMA GEMM:  Out[b][M][1024] = A[Mx512] @ B[b]^T -----
// MODE 0: Out bf16 (QKV).  MODE 1: Out fp32 = mp_add(resid, acc).
template <int MODE>
__global__ __launch_bounds__(256) void gemm_bf16(
    const __hip_bfloat16* __restrict__ A, const __hip_bfloat16* __restrict__ B,
    void* __restrict__ Outv, const float* __restrict__ resid, int M) {
  __shared__ __align__(16) char Al[2][16384];
  __shared__ __align__(16) char Bl[2][16384];
  int t = threadIdx.x;
  int w = t >> 6, l = t & 63;
  int l15 = l & 15, lg = l >> 4;
  int wm = w >> 1, wn = w & 1;
  int n0 = blockIdx.x * 128, m0 = blockIdx.y * 128, b = blockIdx.z;
  const char* Ab = (const char*)A + (size_t)m0 * 1024;
  const char* Bb = (const char*)B + (size_t)b * 1048576 + (size_t)n0 * 1024;
  int rl = t >> 3;
  int soff = ((t & 7) * 16) ^ ((rl & 7) << 4);
  const char* asrc = Ab + (size_t)rl * 1024 + soff;
  const char* bsrc = Bb + (size_t)rl * 1024 + soff;

#define STAGE(bi, k0b)                                                    \
  do {                                                                    \
    _Pragma("unroll") for (int i = 0; i < 4; ++i) {                       \
      gload16(asrc + (size_t)i * 32768 + (k0b), Al[bi] + i * 4096 + w * 1024); \
      gload16(bsrc + (size_t)i * 32768 + (k0b), Bl[bi] + i * 4096 + w * 1024); \
    }                                                                     \
  } while (0)

  f32x4 acc[4][4];
#pragma unroll
  for (int mi = 0; mi < 4; ++mi)
#pragma unroll
    for (int ni = 0; ni < 4; ++ni) acc[mi][ni] = (f32x4){0.f, 0.f, 0.f, 0.f};

  STAGE(0, 0);
  __syncthreads();

  for (int ks = 0; ks < 8; ++ks) {
    int buf = ks & 1;
    if (ks < 7) STAGE(buf ^ 1, (ks + 1) * 128);
    short8 af[4][2], bf[4][2];
#pragma unroll
    for (int mi = 0; mi < 4; ++mi) {
      int row = wm * 64 + mi * 16 + l15;
      int sw = (row & 7) << 4;
#pragma unroll
      for (int h = 0; h < 2; ++h)
        af[mi][h] = *(const short8*)(Al[buf] + row * 128 + ((h * 64 + lg * 16) ^ sw));
    }
#pragma unroll
    for (int ni = 0; ni < 4; ++ni) {
      int row = wn * 64 + ni * 16 + l15;
      int sw = (row & 7) << 4;
#pragma unroll
      for (int h = 0; h < 2; ++h)
        bf[ni][h] = *(const short8*)(Bl[buf] + row * 128 + ((h * 64 + lg * 16) ^ sw));
    }
    __builtin_amdgcn_s_setprio(1);
#pragma unroll
    for (int mi = 0; mi < 4; ++mi)
#pragma unroll
      for (int ni = 0; ni < 4; ++ni) {
        acc[mi][ni] = __builtin_amdgcn_mfma_f32_16x16x32_bf16(af[mi][0], bf[ni][0], acc[mi][ni], 0, 0, 0);
        acc[mi][ni] = __builtin_amdgcn_mfma_f32_16x16x32_bf16(af[mi][1], bf[ni][1], acc[mi][ni], 0, 0, 0);
      }
    __builtin_amdgcn_s_setprio(0);
    if (ks < 7) __syncthreads();
  }
#undef STAGE

  if (MODE == 0) {
    unsigned short* outb = (unsigned short*)Outv + (size_t)b * M * 1024;
#pragma unroll
    for (int mi = 0; mi < 4; ++mi) {
      int row = m0 + wm * 64 + mi * 16 + lg * 4;
#pragma unroll
      for (int r = 0; r < 4; ++r) {
        unsigned short* orow = outb + (size_t)(row + r) * 1024 + n0 + wn * 64 + l15;
#pragma unroll
        for (int ni = 0; ni < 4; ++ni) orow[ni * 16] = f2bf(acc[mi][ni][r]);
      }
    }
  } else {
    float* outb = (float*)Outv + (size_t)b * M * 1024;
    const float* rb = resid + (size_t)b * M * 1024;
#pragma unroll
    for (int mi = 0; mi < 4; ++mi) {
      int row = m0 + wm * 64 + mi * 16 + lg * 4;
#pragma unroll
      for (int r = 0; r < 4; ++r) {
        float* orow = outb + (size_t)(row + r) * 1024 + n0 + wn * 64 + l15;
        const float* rrow = rb + (size_t)(row + r) * 1024 + n0 + wn * 64 + l15;
#pragma unroll
        for (int ni = 0; ni < 4; ++ni)
          orow[ni * 16] = 0.9191450300180578f * rrow[ni * 16] +
                          0.39391929857916763f * acc[mi][ni][r];
      }
    }
  }
}

// ---------------- fused pixel_norm + repack ---------------------------------
// Block (s-tile 64, g, b). Thread: s16=t&15 -> 4 consecutive s; dg=t>>4 ->
// 4 consecutive d. Reads 8 heads (raw in regs), rsqrt inline.
// g<2: LDS 64x64 transpose per head -> q_sd/k_sd [bn][s][d].
// g==2: direct v_ds [bn][d][s].
__global__ __launch_bounds__(256) void norm_pack(
    const __hip_bfloat16* __restrict__ xp,
    __hip_bfloat16* __restrict__ q_sd, __hip_bfloat16* __restrict__ k_sd,
    __hip_bfloat16* __restrict__ v_ds) {
  __shared__ __align__(16) unsigned short trans[64][68];
  int s0 = blockIdx.x * 64, g = blockIdx.y, b = blockIdx.z;
  int t = threadIdx.x;
  int s16 = t & 15, dg = t >> 4;
  int sl4 = s16 * 4;
  const unsigned short* src = (const unsigned short*)xp +
      (size_t)(b * 1536 + g * 512) * 1024 + s0 + sl4;
  float qm = (g == 0) ? 0.18033688011112042f : 1.0f;  // 0.125*log2(e) in Q

  ushort4_t raw[8][4];
  float f[4][4];
#pragma unroll
  for (int i = 0; i < 4; ++i) {
    int d = dg * 4 + i;
    float ss0 = 0.f, ss1 = 0.f, ss2 = 0.f, ss3 = 0.f;
#pragma unroll
    for (int n = 0; n < 8; ++n) {
      ushort4_t pk = *(const ushort4_t*)(src + (size_t)(n * 64 + d) * 1024);
      raw[n][i] = pk;
      float v0 = bf2f(pk[0]), v1 = bf2f(pk[1]), v2 = bf2f(pk[2]), v3 = bf2f(pk[3]);
      ss0 += v0 * v0; ss1 += v1 * v1; ss2 += v2 * v2; ss3 += v3 * v3;
    }
    f[i][0] = rsqrtf(ss0 * 0.125f + 1e-4f) * qm;
    f[i][1] = rsqrtf(ss1 * 0.125f + 1e-4f) * qm;
    f[i][2] = rsqrtf(ss2 * 0.125f + 1e-4f) * qm;
    f[i][3] = rsqrtf(ss3 * 0.125f + 1e-4f) * qm;
  }

  if (g == 2) {
#pragma unroll
    for (int n = 0; n < 8; ++n) {
      unsigned short* dst = (unsigned short*)v_ds +
          (size_t)((b * 8 + n) * 64) * 1024 + s0 + sl4;
#pragma unroll
      for (int i = 0; i < 4; ++i) {
        int d = dg * 4 + i;
        ushort4_t o;
#pragma unroll
        for (int j = 0; j < 4; ++j) o[j] = f2bf(bf2f(raw[n][i][j]) * f[i][j]);
        *(ushort4_t*)(dst + (size_t)d * 1024) = o;
      }
    }
    return;
  }

  unsigned short* dst0 = (unsigned short*)(g ? k_sd : q_sd) + (size_t)(b * 8) * 65536;
#pragma unroll 1
  for (int n = 0; n < 8; ++n) {
#pragma unroll
    for (int i = 0; i < 4; i += 2) {
#pragma unroll
      for (int j = 0; j < 4; ++j) {
        unsigned short lo = f2bf(bf2f(raw[n][i][j]) * f[i][j]);
        unsigned short hi = f2bf(bf2f(raw[n][i + 1][j]) * f[i + 1][j]);
        *(unsigned*)&trans[sl4 + j][dg * 4 + i] = (unsigned)lo | ((unsigned)hi << 16);
      }
    }
    __syncthreads();
    {
      const unsigned short* rs = &trans[t >> 2][(t & 3) * 16];
      uint2 r0 = *(const uint2*)(rs + 0);
      uint2 r1 = *(const uint2*)(rs + 4);
      uint2 r2 = *(const uint2*)(rs + 8);
      uint2 r3 = *(const uint2*)(rs + 12);
      unsigned short* dst = dst0 + (size_t)n * 65536 +
          (size_t)(s0 + (t >> 2)) * 64 + (t & 3) * 16;
      uint4 o0 = {r0.x, r0.y, r1.x, r1.y};
      uint4 o1 = {r2.x, r2.y, r3.x, r3.y};
      *(uint4*)dst = o0;
      *(uint4*)(dst + 8) = o1;
    }
    __syncthreads();
  }
}

// ---------------- flash attention, bf16 MFMA -------------------------------
// Grid (bn=128 FAST, qb=8): all qb for a bn share an XCD -> K/V L2-local.
// 4 waves; wave w owns 32 q (2 subtiles). Swapped operands.
// Defer-max (THR=11 log2-units), cvt_pk bf16 packing, setprio on MFMA.
__global__ __launch_bounds__(256) void attn_mfma(
    const __hip_bfloat16* __restrict__ q_sd, const __hip_bfloat16* __restrict__ k_sd,
    const __hip_bfloat16* __restrict__ v_ds, __hip_bfloat16* __restrict__ y_t) {
  __shared__ __align__(16) char K_lds[2][8192];
  __shared__ __align__(16) char V_lds[2][8192];
  __shared__ __align__(16) unsigned short Ps[4][32][72];
  int t = threadIdx.x;
  int w = t >> 6, l = t & 63;
  int l15 = l & 15, lg = l >> 4;
  int bn = blockIdx.x, qb = blockIdx.y;
  const char* qg = (const char*)(q_sd + (size_t)bn * 65536);   // [s][d]
  const char* kg = (const char*)(k_sd + (size_t)bn * 65536);   // [s][d]
  const char* vg = (const char*)(v_ds + (size_t)bn * 65536);   // [d][s]

  short8 bq[2][2];
  int qrow_base = qb * 128 + w * 32;
#pragma unroll
  for (int c = 0; c < 2; ++c)
#pragma unroll
    for (int h = 0; h < 2; ++h)
      bq[c][h] = *(const short8*)(qg +
          2 * ((size_t)(qrow_base + c * 16 + l15) * 64 + h * 32 + lg * 8));

  f32x4 o_acc[4][2];
#pragma unroll
  for (int dt = 0; dt < 4; ++dt)
#pragma unroll
    for (int c = 0; c < 2; ++c) o_acc[dt][c] = (f32x4){0.f, 0.f, 0.f, 0.f};
  float m_run[2] = {-1e30f, -1e30f}, l_run[2] = {0.f, 0.f};

  int row = t >> 2;
  int coff = (t & 3) * 32;
  int swr = (row & 7) << 4;
  {
    const char* ksrc = kg + (size_t)t * 32;
    const char* vsrc = vg + (size_t)row * 2048 + coff;
    uint4 a = *(const uint4*)(ksrc);
    uint4 b2 = *(const uint4*)(ksrc + 16);
    uint4 c2 = *(const uint4*)(vsrc);
    uint4 d2 = *(const uint4*)(vsrc + 16);
    *(uint4*)(K_lds[0] + ((t * 32) ^ swr)) = a;
    *(uint4*)(K_lds[0] + ((t * 32 + 16) ^ swr)) = b2;
    *(uint4*)(V_lds[0] + ((t * 32) ^ swr)) = c2;
    *(uint4*)(V_lds[0] + ((t * 32 + 16) ^ swr)) = d2;
  }
  __syncthreads();

  for (int kb = 0; kb < 16; ++kb) {
    int buf = kb & 1;
    uint4 pk0, pk1, pk2, pk3;
    if (kb < 15) {
      const char* ksrc = kg + (size_t)(kb + 1) * 8192 + (size_t)t * 32;
      const char* vsrc = vg + (size_t)row * 2048 + (size_t)(kb + 1) * 128 + coff;
      pk0 = *(const uint4*)(ksrc);
      pk1 = *(const uint4*)(ksrc + 16);
      pk2 = *(const uint4*)(vsrc);
      pk3 = *(const uint4*)(vsrc + 16);
    }
    short8 a_k[4][2];
#pragma unroll
    for (int kt = 0; kt < 4; ++kt) {
      int key = kt * 16 + l15;
      int sw = (key & 7) << 4;
#pragma unroll
      for (int h = 0; h < 2; ++h)
        a_k[kt][h] = *(const short8*)(K_lds[buf] + ((key * 128 + h * 64 + lg * 16) ^ sw));
    }
    f32x4 s_acc[4][2];
    __builtin_amdgcn_s_setprio(1);
#pragma unroll
    for (int kt = 0; kt < 4; ++kt)
#pragma unroll
      for (int c = 0; c < 2; ++c) {
        f32x4 acc = (f32x4){0.f, 0.f, 0.f, 0.f};
        acc = __builtin_amdgcn_mfma_f32_16x16x32_bf16(a_k[kt][0], bq[c][0], acc, 0, 0, 0);
        acc = __builtin_amdgcn_mfma_f32_16x16x32_bf16(a_k[kt][1], bq[c][1], acc, 0, 0, 0);
        s_acc[kt][c] = acc;
      }
    __builtin_amdgcn_s_setprio(0);
#pragma unroll
    for (int c = 0; c < 2; ++c) {
      float mt = -1e30f;
#pragma unroll
      for (int kt = 0; kt < 4; ++kt) {
        f32x4 s4 = s_acc[kt][c];
        mt = fmaxf(mt, fmaxf(fmaxf(s4[0], s4[1]), fmaxf(s4[2], s4[3])));
      }
      mt = fmaxf(mt, __shfl_xor(mt, 16, 64));
      mt = fmaxf(mt, __shfl_xor(mt, 32, 64));
      if (!__all(mt <= m_run[c] + 11.0f)) {   // defer-max: rescale rarely
        float m_new = fmaxf(m_run[c], mt);
        float fsc = exp2f(m_run[c] - m_new);
        m_run[c] = m_new;
        l_run[c] *= fsc;
#pragma unroll
        for (int dt = 0; dt < 4; ++dt)
#pragma unroll
          for (int r = 0; r < 4; ++r) o_acc[dt][c][r] *= fsc;
      }
      float mr = m_run[c];
      float ts = 0.f;
#pragma unroll
      for (int kt = 0; kt < 4; ++kt) {
        float p0 = exp2f(s_acc[kt][c][0] - mr);
        float p1 = exp2f(s_acc[kt][c][1] - mr);
        float p2 = exp2f(s_acc[kt][c][2] - mr);
        float p3 = exp2f(s_acc[kt][c][3] - mr);
        ts += (p0 + p1) + (p2 + p3);
        uint2 pr;
        pr.x = cvt_pk(p0, p1);
        pr.y = cvt_pk(p2, p3);
        *(uint2*)&Ps[w][c * 16 + l15][kt * 16 + lg * 4] = pr;
      }
      ts += __shfl_xor(ts, 16, 64);
      ts += __shfl_xor(ts, 32, 64);
      l_run[c] += ts;
    }
    short8 a_v[4][2];
#pragma unroll
    for (int dt = 0; dt < 4; ++dt) {
      int d = dt * 16 + l15;
      int sw = (d & 7) << 4;
#pragma unroll
      for (int h = 0; h < 2; ++h)
        a_v[dt][h] = *(const short8*)(V_lds[buf] + ((d * 128 + h * 64 + lg * 16) ^ sw));
    }
    short8 pbf[2][2];
#pragma unroll
    for (int c = 0; c < 2; ++c)
#pragma unroll
      for (int h = 0; h < 2; ++h)
        pbf[c][h] = *(const short8*)((const char*)&Ps[w][c * 16 + l15][0] + (lg * 8 + h * 32) * 2);
    __builtin_amdgcn_s_setprio(1);
#pragma unroll
    for (int dt = 0; dt < 4; ++dt)
#pragma unroll
      for (int c = 0; c < 2; ++c) {
        o_acc[dt][c] = __builtin_amdgcn_mfma_f32_16x16x32_bf16(a_v[dt][0], pbf[c][0], o_acc[dt][c], 0, 0, 0);
        o_acc[dt][c] = __builtin_amdgcn_mfma_f32_16x16x32_bf16(a_v[dt][1], pbf[c][1], o_acc[dt][c], 0, 0, 0);
      }
    __builtin_amdgcn_s_setprio(0);
    if (kb < 15) {
      int nb = buf ^ 1;
      *(uint4*)(K_lds[nb] + ((t * 32) ^ swr)) = pk0;
      *(uint4*)(K_lds[nb] + ((t * 32 + 16) ^ swr)) = pk1;
      *(uint4*)(V_lds[nb] + ((t * 32) ^ swr)) = pk2;
      *(uint4*)(V_lds[nb] + ((t * 32 + 16) ^ swr)) = pk3;
    }
    __syncthreads();
  }
  // epilogue: y_t[b][s=q][ch = n*64+d]
  int b_ = bn >> 3, n_ = bn & 7;
#pragma unroll
  for (int c = 0; c < 2; ++c) {
    float invl = 1.0f / l_run[c];
    int q = qb * 128 + w * 32 + c * 16 + l15;
    __hip_bfloat16* yrow = y_t + (size_t)b_ * 524288 + (size_t)q * 512 + n_ * 64 + lg * 4;
#pragma unroll
    for (int dt = 0; dt < 4; ++dt) {
      uint2 pr;
      pr.x = cvt_pk(o_acc[dt][c][0] * invl, o_acc[dt][c][1] * invl);
      pr.y = cvt_pk(o_acc[dt][c][2] * invl, o_acc[dt][c][3] * invl);
      *(uint2*)(yrow + dt * 16) = pr;
    }
  }
}

// ---------------------------------------------------------------------------
extern "C" void kernel_launch(void* const* d_in, const int* in_sizes, int n_in,
                              void* d_out, int out_size, void* d_ws, size_t ws_size,
                              hipStream_t stream) {
  const float* x      = (const float*)d_in[0];  // [16][512][1024]
  const float* w_attn = (const float*)d_in[1];  // [1536][512]
  const float* w_proj = (const float*)d_in[2];  // [512][512]
  float* out = (float*)d_out;

  // workspace (bf16 elements, ~104 MB total)
  __hip_bfloat16* wn_attn = (__hip_bfloat16*)d_ws;        // 1536*512
  __hip_bfloat16* wn_proj = wn_attn + 786432;             // 512*512
  __hip_bfloat16* x_t     = wn_proj + 262144;             // 16*1024*512
  __hip_bfloat16* v_ds    = x_t;                          // alias (x_t dead after gemm<0>)
  __hip_bfloat16* xp      = x_t + 8388608;                // 16*1536*1024 bf16
  __hip_bfloat16* y_t     = xp;                           // alias (xp dead after norm_pack)
  __hip_bfloat16* q_sd    = xp + 25165824;                // 16*8*1024*64
  __hip_bfloat16* k_sd    = q_sd + 8388608;

  wnorm_kernel<<<dim3(2048), dim3(256), 0, stream>>>(w_attn, w_proj, wn_attn, wn_proj);
  xt_kernel<<<dim3(16, 8, 16), dim3(256), 0, stream>>>(x, x_t);
  gemm_bf16<0><<<dim3(8, 12, 16), dim3(256), 0, stream>>>(wn_attn, x_t, xp, nullptr, 1536);
  norm_pack<<<dim3(16, 3, 16), dim3(256), 0, stream>>>(xp, q_sd, k_sd, v_ds);
  attn_mfma<<<dim3(128, 8), dim3(256), 0, stream>>>(q_sd, k_sd, v_ds, y_t);
  gemm_bf16<1><<<dim3(8, 4, 16), dim3(256), 0, stream>>>(wn_proj, y_t, out, x, 512);
}